// Round 10
// baseline (111.337 us; speedup 1.0000x reference)
//
#include <hip/hip_runtime.h>
#include <hip/hip_bf16.h>
#include <stdint.h>

#define B_ 8
#define C_ 512
#define N_ 2048

typedef __bf16 bf16_t;
typedef bf16_t bf16x8 __attribute__((ext_vector_type(8)));
typedef bf16_t bf16x4 __attribute__((ext_vector_type(4)));
typedef float f32x4 __attribute__((ext_vector_type(4)));

// ---------------------------------------------------------------------------
// weights_kernel (1 dispatch): blocks 0..63 transpose-cast Wq (64x64 tiles),
// blocks 64..127 cast Wk, blocks 128..191 cast Wv.
// ---------------------------------------------------------------------------
__global__ __launch_bounds__(256) void weights_kernel(
    const float* __restrict__ wq, const float* __restrict__ wk,
    const float* __restrict__ wv, bf16_t* __restrict__ WqT,
    bf16_t* __restrict__ Wkb, bf16_t* __restrict__ Wvb)
{
    __shared__ bf16_t tile[64][65];
    const int t = blockIdx.x;
    const int tid = threadIdx.x;
    if (t < 64) {
        const int i0 = (t & 7) * 64, c0 = (t >> 3) * 64;
        const int cx = (tid & 15) * 4, ry = tid >> 4;
#pragma unroll
        for (int r = ry; r < 64; r += 16) {
            float4 f = *(const float4*)&wq[(size_t)(c0 + r) * C_ + i0 + cx];
            tile[r][cx + 0] = (bf16_t)f.x; tile[r][cx + 1] = (bf16_t)f.y;
            tile[r][cx + 2] = (bf16_t)f.z; tile[r][cx + 3] = (bf16_t)f.w;
        }
        __syncthreads();
#pragma unroll
        for (int r = ry; r < 64; r += 16) {
            bf16x4 o;
            o[0] = tile[cx + 0][r]; o[1] = tile[cx + 1][r];
            o[2] = tile[cx + 2][r]; o[3] = tile[cx + 3][r];
            *(bf16x4*)&WqT[(size_t)(i0 + r) * C_ + c0 + cx] = o;
        }
    } else {
        int j = t - 64;
        const float* src = (j < 64) ? wk : wv;
        bf16_t* dst = (j < 64) ? Wkb : Wvb;
        j &= 63;
#pragma unroll
        for (int p = 0; p < 4; ++p) {
            const int i = j * 4096 + p * 1024 + tid * 4;
            float4 f = *(const float4*)(src + i);
            bf16x4 o;
            o[0] = (bf16_t)f.x; o[1] = (bf16_t)f.y;
            o[2] = (bf16_t)f.z; o[3] = (bf16_t)f.w;
            *(bf16x4*)(dst + i) = o;
        }
    }
}

// ---------------------------------------------------------------------------
// prep_q: q fp32 [B][C][N] -> qT bf16 [B][N][C]  AND  qc bf16 [B][C][N].
// ---------------------------------------------------------------------------
__global__ __launch_bounds__(256) void prep_q_kernel(
    const float* __restrict__ q, bf16_t* __restrict__ qT, bf16_t* __restrict__ qc)
{
    __shared__ bf16_t tile[64][65];
    const int b = blockIdx.z;
    const float* src = q + (size_t)b * C_ * N_;
    bf16_t* dT = qT + (size_t)b * N_ * C_;
    bf16_t* dc = qc + (size_t)b * C_ * N_;
    const int n0 = blockIdx.x * 64, c0 = blockIdx.y * 64;
    const int t = threadIdx.x;
    const int cx = (t & 15) * 4, ry = t >> 4;
#pragma unroll
    for (int r = ry; r < 64; r += 16) {
        float4 f = *(const float4*)&src[(size_t)(c0 + r) * N_ + n0 + cx];
        bf16x4 o;
        o[0] = (bf16_t)f.x; o[1] = (bf16_t)f.y;
        o[2] = (bf16_t)f.z; o[3] = (bf16_t)f.w;
        tile[r][cx + 0] = o[0]; tile[r][cx + 1] = o[1];
        tile[r][cx + 2] = o[2]; tile[r][cx + 3] = o[3];
        *(bf16x4*)&dc[(size_t)(c0 + r) * N_ + n0 + cx] = o;
    }
    __syncthreads();
#pragma unroll
    for (int r = ry; r < 64; r += 16) {
        bf16x4 o;
        o[0] = tile[cx + 0][r]; o[1] = tile[cx + 1][r];
        o[2] = tile[cx + 2][r]; o[3] = tile[cx + 3][r];
        *(bf16x4*)&dT[(size_t)(n0 + r) * C_ + c0 + cx] = o;
    }
}

// ---------------------------------------------------------------------------
// gemm_dkv: Dp[b*8+sp][i,j] = sum_{n in split sp} k[b,i,n]*v[b,j,n].
// fp32 inputs via global_load_lds DMA. BK=32 (2x16 KB LDS), split-K 8 ->
// 1024 blocks, 4 blocks/CU resident (launch_bounds(256,4); VGPR cap 128,
// r9 measured 96 -> no spill). Proven 2-barrier sync; chunk swizzle
// slot = c ^ (r&7) on 16B chunks (8/row). sk8/sv8 per-split row sums by
// edge blocks from staged LDS (split-indexed, no atomics).
// XCD-chunked logical mapping: l = (f&7)*128 + (f>>3) -> each XCD owns
// whole (b,sp) groups; 16 blocks sharing k/v panels on one L2.
// ---------------------------------------------------------------------------
__global__ __launch_bounds__(256, 4) void gemm_dkv(
    const float* __restrict__ Kin, const float* __restrict__ Vin,
    bf16_t* __restrict__ Dp, float* __restrict__ sk8, float* __restrict__ sv8)
{
    __shared__ __align__(16) float As[128 * 32];   // 16 KB
    __shared__ __align__(16) float Bs[128 * 32];   // 16 KB

    const int f = blockIdx.x;
    const int l = (f & 7) * 128 + (f >> 3);
    const int bz = l >> 7;
    const int rem = l & 127;
    const int sp = rem >> 4;
    const int t4 = rem & 15;
    const int m0 = (t4 >> 2) * 128, n0 = (t4 & 3) * 128;
    const int kbeg = sp * 256;

    const int tid = threadIdx.x, lane = tid & 63, wave = tid >> 6;
    const int wr = wave >> 1, wc = wave & 1;

    const float* Ab = Kin + (size_t)bz * C_ * N_;
    const float* Bb = Vin + (size_t)bz * C_ * N_;

    f32x4 acc[4][4];
#pragma unroll
    for (int i = 0; i < 4; ++i)
#pragma unroll
        for (int j = 0; j < 4; ++j) acc[i][j] = 0.f;

    // staging: pass p (0..3) covers rows p*32 + (tid>>3); dest tid*16 + p*4096;
    // source chunk cs = (tid&7) ^ (row&7)   [slot s holds chunk s^(r&7)]
    const int prow = tid >> 3;                      // 0..31
    const int cs   = (tid & 7) ^ (prow & 7);
    const int ldso = tid * 16;

    const int srr = tid >> 1, hh = tid & 1;         // row-sum coords
    float hsA = 0.f, hsB = 0.f;
    const bool doA = (n0 == 0), doB = (m0 == 0);

    for (int t = 0; t < 8; ++t) {
        const float* ga = Ab + (size_t)(m0 + prow) * N_ + kbeg + t * 32 + cs * 4;
        const float* gb = Bb + (size_t)(n0 + prow) * N_ + kbeg + t * 32 + cs * 4;
#pragma unroll
        for (int p = 0; p < 4; ++p)
            __builtin_amdgcn_global_load_lds(
                (const __attribute__((address_space(1))) void*)(ga + (size_t)p * 32 * N_),
                (__attribute__((address_space(3))) void*)((char*)As + ldso + p * 4096),
                16, 0, 0);
#pragma unroll
        for (int p = 0; p < 4; ++p)
            __builtin_amdgcn_global_load_lds(
                (const __attribute__((address_space(1))) void*)(gb + (size_t)p * 32 * N_),
                (__attribute__((address_space(3))) void*)((char*)Bs + ldso + p * 4096),
                16, 0, 0);
        __syncthreads();

        {
            bf16x8 af[4], bfr[4];
            const int c1 = (lane >> 4) * 2;
#pragma unroll
            for (int m = 0; m < 4; ++m) {
                const int r = wr * 64 + (lane & 15) + m * 16;
                f32x4 lo = *(const f32x4*)((const char*)As + r * 128 + ((c1 ^ (r & 7)) << 4));
                f32x4 hi = *(const f32x4*)((const char*)As + r * 128 + (((c1 + 1) ^ (r & 7)) << 4));
                bf16x8 fr;
                fr[0] = (bf16_t)lo[0]; fr[1] = (bf16_t)lo[1];
                fr[2] = (bf16_t)lo[2]; fr[3] = (bf16_t)lo[3];
                fr[4] = (bf16_t)hi[0]; fr[5] = (bf16_t)hi[1];
                fr[6] = (bf16_t)hi[2]; fr[7] = (bf16_t)hi[3];
                af[m] = fr;
            }
#pragma unroll
            for (int n = 0; n < 4; ++n) {
                const int r = wc * 64 + (lane & 15) + n * 16;
                f32x4 lo = *(const f32x4*)((const char*)Bs + r * 128 + ((c1 ^ (r & 7)) << 4));
                f32x4 hi = *(const f32x4*)((const char*)Bs + r * 128 + (((c1 + 1) ^ (r & 7)) << 4));
                bf16x8 fr;
                fr[0] = (bf16_t)lo[0]; fr[1] = (bf16_t)lo[1];
                fr[2] = (bf16_t)lo[2]; fr[3] = (bf16_t)lo[3];
                fr[4] = (bf16_t)hi[0]; fr[5] = (bf16_t)hi[1];
                fr[6] = (bf16_t)hi[2]; fr[7] = (bf16_t)hi[3];
                bfr[n] = fr;
            }
#pragma unroll
            for (int m = 0; m < 4; ++m)
#pragma unroll
                for (int n = 0; n < 4; ++n)
                    acc[m][n] = __builtin_amdgcn_mfma_f32_16x16x32_bf16(
                        af[m], bfr[n], acc[m][n], 0, 0, 0);
        }

        // row sums from staged tiles (swizzle is within-row permutation)
        if (doA) {
#pragma unroll
            for (int u = 0; u < 4; ++u) {
                const int slot = ((hh * 4 + u) + srr) & 7;
                f32x4 vv = *(const f32x4*)((const char*)As + srr * 128 + slot * 16);
                hsA += vv[0] + vv[1] + vv[2] + vv[3];
            }
        }
        if (doB) {
#pragma unroll
            for (int u = 0; u < 4; ++u) {
                const int slot = ((hh * 4 + u) + srr) & 7;
                f32x4 vv = *(const f32x4*)((const char*)Bs + srr * 128 + slot * 16);
                hsB += vv[0] + vv[1] + vv[2] + vv[3];
            }
        }
        __syncthreads();
    }

    const int rj = (lane >> 4) * 4;
    const int cc = lane & 15;
    const size_t sCC = (size_t)C_ * C_;
    const int z = bz * 8 + sp;
#pragma unroll
    for (int m = 0; m < 4; ++m) {
#pragma unroll
        for (int n = 0; n < 4; ++n) {
            const int col = n0 + wc * 64 + n * 16 + cc;
            f32x4 vv = acc[m][n];
#pragma unroll
            for (int j = 0; j < 4; ++j) {
                const int row = m0 + wr * 64 + m * 16 + rj + j;
                Dp[(size_t)z * sCC + (size_t)row * C_ + col] = (bf16_t)vv[j];
            }
        }
    }
    if (doA) {
        hsA += __shfl_xor(hsA, 1, 64);
        if (!hh) sk8[(size_t)(sp * B_ + bz) * C_ + m0 + srr] = hsA;
    }
    if (doB) {
        hsB += __shfl_xor(hsB, 1, 64);
        if (!hh) sv8[(size_t)(sp * B_ + bz) * C_ + n0 + srr] = hsB;
    }
}

// ---------------------------------------------------------------------------
// reduce_mv: blocks 0..1023 sum the 8 split-K partials (Dp -> D);
// blocks 1024..1039 compute u[b] = Wv.(sum_sp sv8), w[b] = Wk.(sum_sp sk8).
// ---------------------------------------------------------------------------
__global__ __launch_bounds__(256) void reduce_mv_kernel(
    const bf16_t* __restrict__ Pt, bf16_t* __restrict__ Out,
    const bf16_t* __restrict__ Wvb, const bf16_t* __restrict__ Wkb,
    const float* __restrict__ sk8, const float* __restrict__ sv8,
    float* __restrict__ u, float* __restrict__ w)
{
    __shared__ float svec[C_];
    const size_t sCC = (size_t)C_ * C_;
    const int bid = blockIdx.x, tid = threadIdx.x;
    if (bid < 1024) {
        size_t idx = ((size_t)bid * 256 + tid) * 8;
        size_t b = idx / sCC;
        size_t r = idx - b * sCC;
        const bf16_t* base = Pt + (b * 8) * sCC + r;
        float acc[8];
#pragma unroll
        for (int j = 0; j < 8; ++j) acc[j] = 0.f;
#pragma unroll
        for (int s = 0; s < 8; ++s) {
            bf16x8 pv = *(const bf16x8*)(base + (size_t)s * sCC);
#pragma unroll
            for (int j = 0; j < 8; ++j) acc[j] += (float)pv[j];
        }
        bf16x8 o;
#pragma unroll
        for (int j = 0; j < 8; ++j) o[j] = (bf16_t)acc[j];
        *(bf16x8*)(Out + idx) = o;
    } else {
        const int b2 = bid - 1024, b = b2 >> 1, sel = b2 & 1;
        const float* s4 = (sel ? sk8 : sv8) + (size_t)b * C_;
        const size_t st = (size_t)B_ * C_;
#pragma unroll
        for (int rr = 0; rr < 2; ++rr) {
            const int j = tid * 2 + rr;
            float s = 0.f;
#pragma unroll
            for (int sp = 0; sp < 8; ++sp) s += s4[sp * st + j];
            svec[j] = s;
        }
        __syncthreads();
        const bf16_t* W = sel ? Wkb : Wvb;
        float* o = (sel ? w : u) + (size_t)b * C_;
        const int c = tid * 2;
#pragma unroll
        for (int rr = 0; rr < 2; ++rr) {
            const bf16_t* row = W + (size_t)(c + rr) * C_;
            float acc = 0.f;
            for (int j = 0; j < C_; j += 8) {
                bf16x8 vv = *(const bf16x8*)(row + j);
#pragma unroll
                for (int e = 0; e < 8; ++e) acc += (float)vv[e] * svec[j + e];
            }
            o[c + rr] = acc;
        }
    }
}

// ---------------------------------------------------------------------------
// 64x64-tile NT bf16 GEMM (r8-proven). K = 512 fixed.
// EPI 0: bf16 out.  EPI 1: + rank-1 (St epilogue).
// EPI 2: bf16 out; blockIdx.x==0 blocks also compute h = St.bq from the
//        same LDS A-tiles.
// ---------------------------------------------------------------------------
template <int EPI>
__global__ __launch_bounds__(256) void gemm64_nt(
    const bf16_t* __restrict__ A, const bf16_t* __restrict__ Bm,
    bf16_t* __restrict__ Cout, size_t sA, size_t sB, size_t sC,
    const float* __restrict__ e0, const float* __restrict__ e1,
    const float* __restrict__ e2, const float* __restrict__ e3,
    const float* __restrict__ bqv, float* __restrict__ hout)
{
    __shared__ __align__(16) bf16_t As[64 * 64];   // 8 KB
    __shared__ __align__(16) bf16_t Bs[64 * 64];

    const int tid = threadIdx.x, lane = tid & 63, wave = tid >> 6;
    const int wr = wave >> 1, wc = wave & 1;
    const int bz = blockIdx.z;
    const int m0 = blockIdx.y * 64, n0 = blockIdx.x * 64;
    const int K = C_;

    const bf16_t* Ab = A + (size_t)bz * sA;
    const bf16_t* Bb = Bm + (size_t)bz * sB;

    f32x4 acc[2][2];
#pragma unroll
    for (int i = 0; i < 2; ++i)
#pragma unroll
        for (int j = 0; j < 2; ++j) acc[i][j] = 0.f;

    const int srow = tid >> 3;
    const int scol = ((tid & 7) ^ (srow & 7)) * 8;
    const int ldso = tid * 16;

    float hacc = 0.f;
    const bool doH = (EPI == 2) && (blockIdx.x == 0);

    for (int t = 0; t < 8; ++t) {
        const bf16_t* ga = Ab + (size_t)(m0 + srow) * K + t * 64 + scol;
        const bf16_t* gb = Bb + (size_t)(n0 + srow) * K + t * 64 + scol;
#pragma unroll
        for (int p = 0; p < 2; ++p)
            __builtin_amdgcn_global_load_lds(
                (const __attribute__((address_space(1))) void*)(ga + (size_t)p * 32 * K),
                (__attribute__((address_space(3))) void*)((char*)As + ldso + p * 4096),
                16, 0, 0);
#pragma unroll
        for (int p = 0; p < 2; ++p)
            __builtin_amdgcn_global_load_lds(
                (const __attribute__((address_space(1))) void*)(gb + (size_t)p * 32 * K),
                (__attribute__((address_space(3))) void*)((char*)Bs + ldso + p * 4096),
                16, 0, 0);
        __syncthreads();

#pragma unroll
        for (int kk = 0; kk < 64; kk += 32) {
            bf16x8 af[2], bfr[2];
            const int kcol = kk + (lane >> 4) * 8;
            const int kc = kcol >> 3;
#pragma unroll
            for (int m = 0; m < 2; ++m) {
                const int r = wr * 32 + (lane & 15) + m * 16;
                af[m] = *(const bf16x8*)((const char*)As + r * 128 +
                                         ((kc ^ (r & 7)) << 4));
            }
#pragma unroll
            for (int n = 0; n < 2; ++n) {
                const int r = wc * 32 + (lane & 15) + n * 16;
                bfr[n] = *(const bf16x8*)((const char*)Bs + r * 128 +
                                          ((kc ^ (r & 7)) << 4));
            }
#pragma unroll
            for (int m = 0; m < 2; ++m)
#pragma unroll
                for (int n = 0; n < 2; ++n)
                    acc[m][n] = __builtin_amdgcn_mfma_f32_16x16x32_bf16(
                        af[m], bfr[n], acc[m][n], 0, 0, 0);
        }
        if (doH) {
            const int rr = tid >> 2, qq = tid & 3;
#pragma unroll
            for (int u = 0; u < 2; ++u) {
                const int c = qq * 2 + u;
                bf16x8 av = *(const bf16x8*)((const char*)As + rr * 128 +
                                             ((c ^ (rr & 7)) << 4));
                const float* bp = bqv + t * 64 + c * 8;
#pragma unroll
                for (int e = 0; e < 8; ++e) hacc += (float)av[e] * bp[e];
            }
        }
        __syncthreads();
    }

    const int rj = (lane >> 4) * 4;
    const int cc = lane & 15;
#pragma unroll
    for (int m = 0; m < 2; ++m) {
#pragma unroll
        for (int n = 0; n < 2; ++n) {
            const int col = n0 + wc * 32 + n * 16 + cc;
            f32x4 vv = acc[m][n];
#pragma unroll
            for (int j = 0; j < 4; ++j) {
                const int row = m0 + wr * 32 + m * 16 + rj + j;
                float val = vv[j];
                if (EPI == 1)
                    val += e0[bz * C_ + row] * e1[col] +
                           e2[row] * (e3[bz * C_ + col] + 2048.0f * e1[col]);
                Cout[(size_t)bz * sC + (size_t)row * C_ + col] = (bf16_t)val;
            }
        }
    }
    if (doH) {
        hacc += __shfl_xor(hacc, 1, 64);
        hacc += __shfl_xor(hacc, 2, 64);
        if ((tid & 3) == 0) hout[bz * C_ + m0 + (tid >> 2)] = hacc;
    }
}

// ---------------------------------------------------------------------------
// Final GEMM: out[c,n] = sum_i HT[c,i]*qT[n,i] + h[b][c] + (float)qc[c,n].
// 1-D swizzled grid (512).
// ---------------------------------------------------------------------------
__global__ __launch_bounds__(256) void gemm_final(
    const bf16_t* __restrict__ A, const bf16_t* __restrict__ Bm,
    float* __restrict__ Cout, const bf16_t* __restrict__ qc,
    const float* __restrict__ hvec)
{
    __shared__ __align__(16) bf16_t As[128 * 64];
    __shared__ __align__(16) bf16_t Bs[128 * 64];

    const int f = blockIdx.x;
    const int xcd = f & 7, sl = f >> 3;
    const int g = xcd + 8 * (sl >> 2);
    const int m0 = (sl & 3) * 128;
    const int bz = g >> 4;
    const int n0 = (g & 15) * 128;
    const int K = C_;

    const int tid = threadIdx.x, lane = tid & 63, wave = tid >> 6;
    const int wr = wave >> 1, wc = wave & 1;

    const bf16_t* Ab = A + (size_t)bz * ((size_t)C_ * C_);
    const bf16_t* Bb = Bm + (size_t)bz * ((size_t)N_ * C_);

    f32x4 acc[4][4];
#pragma unroll
    for (int i = 0; i < 4; ++i)
#pragma unroll
        for (int j = 0; j < 4; ++j) acc[i][j] = 0.f;

    const int srow = tid >> 3;
    const int scol = ((tid & 7) ^ (srow & 7)) * 8;
    const int ldso = tid * 16;

    for (int t = 0; t < 8; ++t) {
        const bf16_t* ga = Ab + (size_t)(m0 + srow) * K + t * 64 + scol;
        const bf16_t* gb = Bb + (size_t)(n0 + srow) * K + t * 64 + scol;
#pragma unroll
        for (int p = 0; p < 4; ++p)
            __builtin_amdgcn_global_load_lds(
                (const __attribute__((address_space(1))) void*)(ga + (size_t)p * 32 * K),
                (__attribute__((address_space(3))) void*)((char*)As + ldso + p * 4096),
                16, 0, 0);
#pragma unroll
        for (int p = 0; p < 4; ++p)
            __builtin_amdgcn_global_load_lds(
                (const __attribute__((address_space(1))) void*)(gb + (size_t)p * 32 * K),
                (__attribute__((address_space(3))) void*)((char*)Bs + ldso + p * 4096),
                16, 0, 0);
        __syncthreads();

#pragma unroll
        for (int kk = 0; kk < 64; kk += 32) {
            bf16x8 af[4], bfr[4];
            const int kcol = kk + (lane >> 4) * 8;
            const int kc = kcol >> 3;
#pragma unroll
            for (int m = 0; m < 4; ++m) {
                const int r = wr * 64 + (lane & 15) + m * 16;
                af[m] = *(const bf16x8*)((const char*)As + r * 128 +
                                         ((kc ^ (r & 7)) << 4));
            }
#pragma unroll
            for (int n = 0; n < 4; ++n) {
                const int r = wc * 64 + (lane & 15) + n * 16;
                bfr[n] = *(const bf16x8*)((const char*)Bs + r * 128 +
                                          ((kc ^ (r & 7)) << 4));
            }
#pragma unroll
            for (int m = 0; m < 4; ++m)
#pragma unroll
                for (int n = 0; n < 4; ++n)
                    acc[m][n] = __builtin_amdgcn_mfma_f32_16x16x32_bf16(
                        af[m], bfr[n], acc[m][n], 0, 0, 0);
        }
        __syncthreads();
    }

    const int rj = (lane >> 4) * 4;
    const int cc = lane & 15;
    const size_t ob = (size_t)bz * ((size_t)C_ * N_);
#pragma unroll
    for (int m = 0; m < 4; ++m) {
#pragma unroll
        for (int n = 0; n < 4; ++n) {
            const int col = n0 + wc * 64 + n * 16 + cc;
            f32x4 vv = acc[m][n];
#pragma unroll
            for (int j = 0; j < 4; ++j) {
                const int row = m0 + wr * 64 + m * 16 + rj + j;
                const size_t o = ob + (size_t)row * N_ + col;
                Cout[o] = vv[j] + hvec[bz * C_ + row] + (float)qc[o];
            }
        }
    }
}

// ---------------------------------------------------------------------------
extern "C" void kernel_launch(void* const* d_in, const int* in_sizes, int n_in,
                              void* d_out, int out_size, void* d_ws, size_t ws_size,
                              hipStream_t stream)
{
    (void)in_sizes; (void)n_in; (void)out_size; (void)ws_size;
    const float* q  = (const float*)d_in[0];
    const float* k  = (const float*)d_in[1];
    const float* v  = (const float*)d_in[2];
    const float* wq = (const float*)d_in[3];
    const float* bq = (const float*)d_in[4];
    const float* wk = (const float*)d_in[5];
    const float* bk = (const float*)d_in[6];
    const float* wv = (const float*)d_in[7];
    const float* bv = (const float*)d_in[8];
    float* out = (float*)d_out;

    char* ws = (char*)d_ws;
    const size_t WSZ = (size_t)C_ * C_ * 2;            // 512 KB
    const size_t TSZ = (size_t)B_ * N_ * C_ * 2;       // 16.78 MB
    const size_t SCZ = (size_t)B_ * C_ * C_ * 2;       // 4.19 MB
    const size_t VSZ = (size_t)B_ * C_ * 4;            // 16 KB
    const size_t sCC = (size_t)C_ * C_;
    size_t off = 0;
    bf16_t* Wkb  = (bf16_t*)(ws + off); off += WSZ;
    bf16_t* Wvb  = (bf16_t*)(ws + off); off += WSZ;
    bf16_t* WqTb = (bf16_t*)(ws + off); off += WSZ;
    bf16_t* qT   = (bf16_t*)(ws + off); off += TSZ;
    bf16_t* qc   = (bf16_t*)(ws + off); off += TSZ;
    bf16_t* Dp   = (bf16_t*)(ws + off); off += 2 * TSZ;   // 64 x sCC partials
    bf16_t* D    = (bf16_t*)(ws + off); off += SCZ;
    float*  sk8  = (float*)(ws + off);  off += 8 * VSZ;
    float*  sv8  = (float*)(ws + off);  off += 8 * VSZ;
    float*  uu   = (float*)(ws + off);  off += VSZ;
    float*  wwv  = (float*)(ws + off);  off += VSZ;
    float*  hb   = (float*)(ws + off);  off += VSZ;
    // P1 / St / HT overlay Dp (dead after reduce_mv): 24*sCC <= 64*sCC
    bf16_t* P1 = Dp;
    bf16_t* St = Dp + (size_t)B_ * sCC;
    bf16_t* HT = Dp + 2 * (size_t)B_ * sCC;

    const dim3 blk(256);

    // 1. weights (Wk,Wv cast + Wq transpose) in one dispatch
    weights_kernel<<<dim3(192), blk, 0, stream>>>(wq, wk, wv, WqTb, Wkb, Wvb);

    // 2. q -> qT (bf16 [B,N,C]) + qc (bf16 [B,C,N])
    prep_q_kernel<<<dim3(N_ / 64, C_ / 64, B_), blk, 0, stream>>>(q, qT, qc);

    // 3. D partials from fp32 k,v directly (split-K 8, BK=32, 4 blocks/CU)
    gemm_dkv<<<dim3(1024), blk, 0, stream>>>(k, v, Dp, sk8, sv8);

    // 4. reduce Dp -> D;  u = Wv.sv, w = Wk.sk  (one dispatch)
    reduce_mv_kernel<<<dim3(1040), blk, 0, stream>>>(
        Dp, D, Wvb, Wkb, sk8, sv8, uu, wwv);

    // 5. P1[c2,i] = sum_j Wv[c2,j] D[i,j]
    gemm64_nt<0><<<dim3(C_ / 64, C_ / 64, B_), blk, 0, stream>>>(
        Wvb, D, P1, 0, sCC, sCC, nullptr, nullptr, nullptr, nullptr, nullptr, nullptr);

    // 6. St = P1.Wk^T + u bk^T + bv (w + N bk)^T
    gemm64_nt<1><<<dim3(C_ / 64, C_ / 64, B_), blk, 0, stream>>>(
        P1, Wkb, St, sCC, 0, sCC, uu, bk, bv, wwv, nullptr, nullptr);

    // 7. HT = St.Wq  (+ h = St.bq by x==0 blocks)
    gemm64_nt<2><<<dim3(C_ / 64, C_ / 64, B_), blk, 0, stream>>>(
        St, WqTb, HT, sCC, 0, sCC, nullptr, nullptr, nullptr, nullptr, bq, hb);

    // 8. out = HT.qT^T + h + qc   (fp32, final layout, XCD-swizzled)
    gemm_final<<<dim3(512), blk, 0, stream>>>(HT, qT, out, qc, hb);
}